// Round 2
// baseline (1169.748 us; speedup 1.0000x reference)
//
#include <hip/hip_runtime.h>
#include <hip/hip_bf16.h>

#define B_    1024
#define H_    1024
#define VOUT  50000
#define VINP  32000
#define SRC_  256

#define BM 128
#define BN 128
#define BKK 32

typedef __bf16 bf16x8 __attribute__((ext_vector_type(8)));
typedef __bf16 bf16x4 __attribute__((ext_vector_type(4)));
typedef float  f32x4  __attribute__((ext_vector_type(4)));

// ---------------- init: src_inp=-1, rowsum=0 --------------------------------
__global__ void init_kernel(int* __restrict__ src_inp,
                            float* __restrict__ rowsum)
{
    int i = blockIdx.x * blockDim.x + threadIdx.x;
    if (i < VOUT) src_inp[i] = -1;
    if (i < B_)  rowsum[i] = 0.0f;
}

__global__ void scat_max_kernel(const int* __restrict__ i2a, int* __restrict__ src_inp) {
    int v = blockIdx.x * blockDim.x + threadIdx.x;
    if (v < VINP) atomicMax(&src_inp[i2a[v]], v);
}

// ---------------- GEMM: out_scores = x @ W[out_map].T + b[out_map] ----------
// writes gen_masked = scores - 1e6*amask and accumulates rowsum[m] += exp(score)
__global__ __launch_bounds__(256) void gemm_kernel(
    const float* __restrict__ x, const float* __restrict__ W,
    const float* __restrict__ bias, const int* __restrict__ out_map,
    const int* __restrict__ amask,
    float* __restrict__ out_scores, float* __restrict__ gen_masked,
    float* __restrict__ rowsum)
{
    __shared__ __bf16 As[BM * BKK];   // unpadded: rows of 64B -> conflict-free
    __shared__ __bf16 Bs[BN * BKK];

    // XCD swizzle: linear id -> XCD = id%8 (round-robin). Give XCD r the
    // column tiles [49r, 49r+49) with all 8 row-blocks, so the gathered
    // W tile is fetched into ONE L2 and shared by the 8 row-blocks.
    const int id = (int)(blockIdx.x + (blockIdx.y << 3));   // gridDim.x == 8
    const int g  = id >> 3;
    const int by = (id & 7) * 49 + (g >> 3);                // 0..391
    if (by >= 391) return;                                  // 8 pad blocks idle
    const int bx = g & 7;
    const int m0 = bx * BM;
    const int n0 = by * BN;

    const int t  = threadIdx.x;
    const int tr = t >> 3;            // 0..31
    const int tk = (t & 7) << 2;      // 0,4,..,28

    const float* xrow[4];
    const float* wrow[4];
    #pragma unroll
    for (int p = 0; p < 4; ++p) {
        int r = tr + p * 32;
        xrow[p] = x + (size_t)(m0 + r) * H_ + tk;
        int n = n0 + r; if (n >= VOUT) n = VOUT - 1;
        wrow[p] = W + (size_t)out_map[n] * H_ + tk;
    }

    f32x4 acc[4][4];
    #pragma unroll
    for (int i = 0; i < 4; ++i)
        #pragma unroll
        for (int j = 0; j < 4; ++j)
            acc[i][j] = (f32x4){0.f, 0.f, 0.f, 0.f};

    const int wv   = t >> 6;
    const int wm   = (wv >> 1) * 64;
    const int wn   = (wv & 1) * 64;
    const int lane = t & 63;
    const int quad = lane >> 4;
    const int lr   = lane & 15;

    // prefetch k0 = 0
    float4 ar[4], br[4];
    #pragma unroll
    for (int p = 0; p < 4; ++p) {
        ar[p] = *(const float4*)(xrow[p]);
        br[p] = *(const float4*)(wrow[p]);
    }

    for (int k0 = 0; k0 < H_; k0 += BKK) {
        // write current registers to LDS (cvt f32->bf16)
        #pragma unroll
        for (int p = 0; p < 4; ++p) {
            int r = tr + p * 32;
            bf16x4 a4, b4;
            a4.x = (__bf16)ar[p].x; a4.y = (__bf16)ar[p].y; a4.z = (__bf16)ar[p].z; a4.w = (__bf16)ar[p].w;
            b4.x = (__bf16)br[p].x; b4.y = (__bf16)br[p].y; b4.z = (__bf16)br[p].z; b4.w = (__bf16)br[p].w;
            *(bf16x4*)(&As[r * BKK + tk]) = a4;
            *(bf16x4*)(&Bs[r * BKK + tk]) = b4;
        }
        __syncthreads();

        // prefetch next k-tile: latency hidden under LDS reads + MFMA
        if (k0 + BKK < H_) {
            #pragma unroll
            for (int p = 0; p < 4; ++p) {
                ar[p] = *(const float4*)(xrow[p] + k0 + BKK);
                br[p] = *(const float4*)(wrow[p] + k0 + BKK);
            }
        }

        bf16x8 af[4], bfr[4];
        #pragma unroll
        for (int i = 0; i < 4; ++i) {
            af[i]  = *(const bf16x8*)(&As[(wm + i * 16 + lr) * BKK + quad * 8]);
            bfr[i] = *(const bf16x8*)(&Bs[(wn + i * 16 + lr) * BKK + quad * 8]);
        }
        // operand-swapped: D row = n-sub (quad*4+reg), D col = m-sub (lr)
        #pragma unroll
        for (int mi = 0; mi < 4; ++mi)
            #pragma unroll
            for (int ni = 0; ni < 4; ++ni)
                acc[mi][ni] = __builtin_amdgcn_mfma_f32_16x16x32_bf16(bfr[ni], af[mi], acc[mi][ni], 0, 0, 0);
        __syncthreads();
    }

    // epilogue: each lane owns 4 consecutive n at fixed m -> float4 stores
    #pragma unroll
    for (int mi = 0; mi < 4; ++mi) {
        const int m = m0 + wm + mi * 16 + lr;
        float psum = 0.0f;
        #pragma unroll
        for (int ni = 0; ni < 4; ++ni) {
            const int n = n0 + wn + ni * 16 + (quad << 2);
            if (n < VOUT) {
                const size_t off = (size_t)m * VOUT + n;
                float4 v;
                v.x = acc[mi][ni][0] + bias[out_map[n + 0]];
                v.y = acc[mi][ni][1] + bias[out_map[n + 1]];
                v.z = acc[mi][ni][2] + bias[out_map[n + 2]];
                v.w = acc[mi][ni][3] + bias[out_map[n + 3]];
                *(float4*)(out_scores + off) = v;
                const int4 am = *(const int4*)(amask + off);
                float4 gm;
                gm.x = v.x - 1000000.0f * (float)am.x;
                gm.y = v.y - 1000000.0f * (float)am.y;
                gm.z = v.z - 1000000.0f * (float)am.z;
                gm.w = v.w - 1000000.0f * (float)am.w;
                *(float4*)(gen_masked + off) = gm;
                psum += __expf(v.x) + __expf(v.y) + __expf(v.z) + __expf(v.w);
            }
        }
        // lanes {lr, lr+16, lr+32, lr+48} share the same m: reduce over quads
        psum += __shfl_xor(psum, 16, 64);
        psum += __shfl_xor(psum, 32, 64);
        if (quad == 0) atomicAdd(rowsum + m, psum);
    }
}

// ---------------- ptr scatter-add + telescoping rowsum correction -----------
// atomics serialize per address, so sum over threads of
// exp(old+a)-exp(old) telescopes exactly to exp(final)-exp(initial).
__global__ void ptr_scatter_kernel(const float* __restrict__ attn,
                                   const int* __restrict__ ctx,
                                   const int* __restrict__ i2a,
                                   const int* __restrict__ src_inp,
                                   float* __restrict__ out_scores,
                                   float* __restrict__ rowsum)
{
    int idx = blockIdx.x * blockDim.x + threadIdx.x;   // B*SRC threads
    int i = idx >> 8;
    int v = ctx[idx];
    int o = i2a[v];
    if (src_inp[o] == v) {
        float a   = attn[idx];
        float old = atomicAdd(out_scores + (size_t)i * VOUT + o, a);
        atomicAdd(rowsum + i, __expf(old + a) - __expf(old));
    }
}

// ---------------- single-pass normalize: p = exp(v) / rowsum ----------------
__global__ __launch_bounds__(256) void norm_kernel(float* __restrict__ probs,
                                                   const float* __restrict__ rowsum)
{
    const int row = blockIdx.x;
    const float inv = 1.0f / rowsum[row];
    float4* p4 = (float4*)(probs + (size_t)row * VOUT);
    const int base = blockIdx.y * 3125;                 // 4 segs * 3125 * 4 = 50000
    for (int i = base + threadIdx.x; i < base + 3125; i += 256) {
        float4 v = p4[i];
        v.x = __expf(v.x) * inv;
        v.y = __expf(v.y) * inv;
        v.z = __expf(v.z) * inv;
        v.w = __expf(v.w) * inv;
        p4[i] = v;
    }
}

// ---------------- launch ----------------------------------------------------
extern "C" void kernel_launch(void* const* d_in, const int* in_sizes, int n_in,
                              void* d_out, int out_size, void* d_ws, size_t ws_size,
                              hipStream_t stream)
{
    const float* x     = (const float*)d_in[0];
    const float* W     = (const float*)d_in[1];
    const float* b     = (const float*)d_in[2];
    const float* attn  = (const float*)d_in[3];
    const int*   ctx   = (const int*)d_in[4];
    const int*   i2a   = (const int*)d_in[5];
    const int*   omap  = (const int*)d_in[6];
    const int*   amask = (const int*)d_in[7];

    float* out_probs  = (float*)d_out;                       // B*VOUT
    float* gen_masked = out_probs + (size_t)B_ * VOUT;       // B*VOUT

    int*   src_inp = (int*)d_ws;                             // VOUT ints
    float* rowsum  = (float*)(src_inp + VOUT);               // B floats

    init_kernel<<<(VOUT + 255) / 256, 256, 0, stream>>>(src_inp, rowsum);
    scat_max_kernel<<<(VINP + 255) / 256, 256, 0, stream>>>(i2a, src_inp);

    dim3 grid(B_ / BM, 392);                                 // padded to 8*392 for swizzle
    gemm_kernel<<<grid, 256, 0, stream>>>(x, W, b, omap, amask,
                                          out_probs, gen_masked, rowsum);

    ptr_scatter_kernel<<<(B_ * SRC_) / 256, 256, 0, stream>>>(attn, ctx, i2a, src_inp,
                                                              out_probs, rowsum);

    norm_kernel<<<dim3(B_, 4), 256, 0, stream>>>(out_probs, rowsum);
}

// Round 3
// 1140.953 us; speedup vs baseline: 1.0252x; 1.0252x over previous
//
#include <hip/hip_runtime.h>
#include <hip/hip_bf16.h>

#define B_    1024
#define H_    1024
#define VOUT  50000
#define VINP  32000
#define SRC_  256

#define BM 128
#define BN 128
#define BKK 32

typedef __bf16 bf16x8 __attribute__((ext_vector_type(8)));
typedef __bf16 bf16x4 __attribute__((ext_vector_type(4)));
typedef float  f32x4  __attribute__((ext_vector_type(4)));

// ---------------- init: src_inp=-1, rowsum=0 --------------------------------
__global__ void init_kernel(int* __restrict__ src_inp,
                            float* __restrict__ rowsum)
{
    int i = blockIdx.x * blockDim.x + threadIdx.x;
    if (i < VOUT) src_inp[i] = -1;
    if (i < B_)  rowsum[i] = 0.0f;
}

__global__ void scat_max_kernel(const int* __restrict__ i2a, int* __restrict__ src_inp) {
    int v = blockIdx.x * blockDim.x + threadIdx.x;
    if (v < VINP) atomicMax(&src_inp[i2a[v]], v);
}

// ---------------- GEMM: out_scores = x @ W[out_map].T + b[out_map] ----------
// 2-deep register prefetch + double-buffered LDS (1 barrier/iter) + XOR swizzle
__global__ __launch_bounds__(256) void gemm_kernel(
    const float* __restrict__ x, const float* __restrict__ W,
    const float* __restrict__ bias, const int* __restrict__ out_map,
    const int* __restrict__ amask,
    float* __restrict__ out_scores, float* __restrict__ gen_masked,
    float* __restrict__ rowsum)
{
    __shared__ __bf16 As[2][BM * BKK];   // rows of 64B, XOR-swizzled in 16B units
    __shared__ __bf16 Bs[2][BN * BKK];

    // XCD swizzle: XCD r owns column tiles [49r,49r+49) x all 8 row-blocks
    const int id = (int)(blockIdx.x + (blockIdx.y << 3));   // gridDim.x == 8
    const int g  = id >> 3;
    const int by = (id & 7) * 49 + (g >> 3);                // 0..391
    if (by >= 391) return;
    const int bx = g & 7;
    const int m0 = bx * BM;
    const int n0 = by * BN;

    const int t  = threadIdx.x;
    const int tr = t >> 3;            // 0..31 (row within 32-row group)
    const int u  = t & 7;             // 8B unit within 64B row
    const int tk = u << 2;            // starting k-elem

    const float* xrow[4];
    const float* wrow[4];
    int scol[4];                      // swizzled LDS elem offset for staging
    #pragma unroll
    for (int p = 0; p < 4; ++p) {
        int r = tr + p * 32;
        xrow[p] = x + (size_t)(m0 + r) * H_ + tk;
        int n = n0 + r; if (n >= VOUT) n = VOUT - 1;
        wrow[p] = W + (size_t)out_map[n] * H_ + tk;
        int gg = (r >> 1) & 3;        // swizzle: 16B-unit ^= (row>>1)&3
        scol[p] = r * BKK + ((((u >> 1) ^ gg) << 3) | ((u & 1) << 2));
    }

    f32x4 acc[4][4];
    #pragma unroll
    for (int i = 0; i < 4; ++i)
        #pragma unroll
        for (int j = 0; j < 4; ++j)
            acc[i][j] = (f32x4){0.f, 0.f, 0.f, 0.f};

    const int wv   = t >> 6;
    const int wm   = (wv >> 1) * 64;
    const int wn   = (wv & 1) * 64;
    const int lane = t & 63;
    const int quad = lane >> 4;
    const int lr   = lane & 15;

    auto stage = [&](int buf, const float4* a, const float4* b) {
        #pragma unroll
        for (int p = 0; p < 4; ++p) {
            bf16x4 a4, b4;
            a4.x = (__bf16)a[p].x; a4.y = (__bf16)a[p].y; a4.z = (__bf16)a[p].z; a4.w = (__bf16)a[p].w;
            b4.x = (__bf16)b[p].x; b4.y = (__bf16)b[p].y; b4.z = (__bf16)b[p].z; b4.w = (__bf16)b[p].w;
            *(bf16x4*)(&As[buf][scol[p]]) = a4;
            *(bf16x4*)(&Bs[buf][scol[p]]) = b4;
        }
    };

    auto compute = [&](int buf) {
        bf16x8 af[4], bfr[4];
        #pragma unroll
        for (int i = 0; i < 4; ++i) {
            int Ra = wm + i * 16 + lr;
            int Rb = wn + i * 16 + lr;
            af[i]  = *(const bf16x8*)(&As[buf][Ra * BKK + ((quad ^ ((Ra >> 1) & 3)) << 3)]);
            bfr[i] = *(const bf16x8*)(&Bs[buf][Rb * BKK + ((quad ^ ((Rb >> 1) & 3)) << 3)]);
        }
        #pragma unroll
        for (int mi = 0; mi < 4; ++mi)
            #pragma unroll
            for (int ni = 0; ni < 4; ++ni)
                acc[mi][ni] = __builtin_amdgcn_mfma_f32_16x16x32_bf16(bfr[ni], af[mi], acc[mi][ni], 0, 0, 0);
    };

    // prologue: two tiles in flight
    float4 a0[4], b0[4], a1[4], b1[4];
    #pragma unroll
    for (int p = 0; p < 4; ++p) {
        a0[p] = *(const float4*)(xrow[p]);
        b0[p] = *(const float4*)(wrow[p]);
        a1[p] = *(const float4*)(xrow[p] + BKK);
        b1[p] = *(const float4*)(wrow[p] + BKK);
    }

    for (int k0 = 0; k0 < H_; k0 += 2 * BKK) {
        // ---- phase A: data k0 (set0/buf0), prefetch k0+64 into set0
        stage(0, a0, b0);
        if (k0 + 2 * BKK < H_) {
            #pragma unroll
            for (int p = 0; p < 4; ++p) {
                a0[p] = *(const float4*)(xrow[p] + k0 + 2 * BKK);
                b0[p] = *(const float4*)(wrow[p] + k0 + 2 * BKK);
            }
        }
        __syncthreads();
        compute(0);

        // ---- phase B: data k0+32 (set1/buf1), prefetch k0+96 into set1
        stage(1, a1, b1);
        if (k0 + 3 * BKK < H_) {
            #pragma unroll
            for (int p = 0; p < 4; ++p) {
                a1[p] = *(const float4*)(xrow[p] + k0 + 3 * BKK);
                b1[p] = *(const float4*)(wrow[p] + k0 + 3 * BKK);
            }
        }
        __syncthreads();
        compute(1);
    }

    // epilogue: each lane owns 4 consecutive n at fixed m -> float4 stores
    #pragma unroll
    for (int mi = 0; mi < 4; ++mi) {
        const int m = m0 + wm + mi * 16 + lr;
        float psum = 0.0f;
        #pragma unroll
        for (int ni = 0; ni < 4; ++ni) {
            const int n = n0 + wn + ni * 16 + (quad << 2);
            if (n < VOUT) {
                const size_t off = (size_t)m * VOUT + n;
                float4 v;
                v.x = acc[mi][ni][0] + bias[out_map[n + 0]];
                v.y = acc[mi][ni][1] + bias[out_map[n + 1]];
                v.z = acc[mi][ni][2] + bias[out_map[n + 2]];
                v.w = acc[mi][ni][3] + bias[out_map[n + 3]];
                *(float4*)(out_scores + off) = v;
                const int4 am = *(const int4*)(amask + off);
                float4 gm;
                gm.x = v.x - 1000000.0f * (float)am.x;
                gm.y = v.y - 1000000.0f * (float)am.y;
                gm.z = v.z - 1000000.0f * (float)am.z;
                gm.w = v.w - 1000000.0f * (float)am.w;
                *(float4*)(gen_masked + off) = gm;
                psum += __expf(v.x) + __expf(v.y) + __expf(v.z) + __expf(v.w);
            }
        }
        psum += __shfl_xor(psum, 16, 64);
        psum += __shfl_xor(psum, 32, 64);
        if (quad == 0) atomicAdd(rowsum + m, psum);
    }
}

// ---------------- ptr scatter-add + telescoping rowsum correction -----------
__global__ void ptr_scatter_kernel(const float* __restrict__ attn,
                                   const int* __restrict__ ctx,
                                   const int* __restrict__ i2a,
                                   const int* __restrict__ src_inp,
                                   float* __restrict__ out_scores,
                                   float* __restrict__ rowsum)
{
    int idx = blockIdx.x * blockDim.x + threadIdx.x;   // B*SRC threads
    int i = idx >> 8;
    int v = ctx[idx];
    int o = i2a[v];
    if (src_inp[o] == v) {
        float a   = attn[idx];
        float old = atomicAdd(out_scores + (size_t)i * VOUT + o, a);
        atomicAdd(rowsum + i, __expf(old + a) - __expf(old));
    }
}

// ---------------- single-pass normalize: p = exp(v) / rowsum ----------------
__global__ __launch_bounds__(256) void norm_kernel(float* __restrict__ probs,
                                                   const float* __restrict__ rowsum)
{
    const int row = blockIdx.x;
    const float inv = 1.0f / rowsum[row];
    float4* p4 = (float4*)(probs + (size_t)row * VOUT);
    const int base = blockIdx.y * 3125;                 // 4 segs * 3125 * 4 = 50000
    for (int i = base + threadIdx.x; i < base + 3125; i += 256) {
        float4 v = p4[i];
        v.x = __expf(v.x) * inv;
        v.y = __expf(v.y) * inv;
        v.z = __expf(v.z) * inv;
        v.w = __expf(v.w) * inv;
        p4[i] = v;
    }
}

// ---------------- launch ----------------------------------------------------
extern "C" void kernel_launch(void* const* d_in, const int* in_sizes, int n_in,
                              void* d_out, int out_size, void* d_ws, size_t ws_size,
                              hipStream_t stream)
{
    const float* x     = (const float*)d_in[0];
    const float* W     = (const float*)d_in[1];
    const float* b     = (const float*)d_in[2];
    const float* attn  = (const float*)d_in[3];
    const int*   ctx   = (const int*)d_in[4];
    const int*   i2a   = (const int*)d_in[5];
    const int*   omap  = (const int*)d_in[6];
    const int*   amask = (const int*)d_in[7];

    float* out_probs  = (float*)d_out;                       // B*VOUT
    float* gen_masked = out_probs + (size_t)B_ * VOUT;       // B*VOUT

    int*   src_inp = (int*)d_ws;                             // VOUT ints
    float* rowsum  = (float*)(src_inp + VOUT);               // B floats

    init_kernel<<<(VOUT + 255) / 256, 256, 0, stream>>>(src_inp, rowsum);
    scat_max_kernel<<<(VINP + 255) / 256, 256, 0, stream>>>(i2a, src_inp);

    dim3 grid(B_ / BM, 392);                                 // 8*392 padded for swizzle
    gemm_kernel<<<grid, 256, 0, stream>>>(x, W, b, omap, amask,
                                          out_probs, gen_masked, rowsum);

    ptr_scatter_kernel<<<(B_ * SRC_) / 256, 256, 0, stream>>>(attn, ctx, i2a, src_inp,
                                                              out_probs, rowsum);

    norm_kernel<<<dim3(B_, 4), 256, 0, stream>>>(out_probs, rowsum);
}

// Round 4
// 1121.719 us; speedup vs baseline: 1.0428x; 1.0171x over previous
//
#include <hip/hip_runtime.h>
#include <hip/hip_bf16.h>

#define B_    1024
#define H_    1024
#define VOUT  50000
#define VINP  32000
#define SRC_  256
#define NPAD  50048            // VOUT padded up to a multiple of 128

#define BM 128
#define BN 128
#define BKK 32
#define NSTEP (H_ / BKK)       // 32

typedef __bf16 bf16x8 __attribute__((ext_vector_type(8)));
typedef float  f32x4  __attribute__((ext_vector_type(4)));

__device__ __forceinline__ void ldsload16(const __bf16* g, __bf16* l) {
    __builtin_amdgcn_global_load_lds(
        (const __attribute__((address_space(1))) void*)g,
        (__attribute__((address_space(3))) void*)l, 16, 0, 0);
}

// ---------------- init: src_inp=-1, rowsum=0 --------------------------------
__global__ void init_kernel(int* __restrict__ src_inp,
                            float* __restrict__ rowsum)
{
    int i = blockIdx.x * blockDim.x + threadIdx.x;
    if (i < VOUT) src_inp[i] = -1;
    if (i < B_)  rowsum[i] = 0.0f;
}

__global__ void scat_max_kernel(const int* __restrict__ i2a, int* __restrict__ src_inp) {
    int v = blockIdx.x * blockDim.x + threadIdx.x;
    if (v < VINP) atomicMax(&src_inp[i2a[v]], v);
}

// ---------------- convert: W_bf[n] = bf16(W[out_map[n]]), source-swizzled ----
// Within each 64B k-chunk (4 x 16B units) the units are permuted by
// XOR with g(n) = (n>>1)&3 -- the same involution the GEMM ds_reads apply.
__global__ __launch_bounds__(256) void conv_w(
    const float* __restrict__ W, const int* __restrict__ omap,
    const float* __restrict__ bias,
    __bf16* __restrict__ wbf, float* __restrict__ bias_g)
{
    int idx = blockIdx.x * 256 + threadIdx.x;   // NPAD*128 16B-units
    int n   = idx >> 7;
    int c7  = idx & 127;                        // unit within row
    bf16x8 v;
    if (n < VOUT) {
        int g = (n >> 1) & 3;
        int chunk = c7 >> 2, w = c7 & 3;
        const float* s = W + (size_t)omap[n] * H_ + chunk * 32 + ((w ^ g) << 3);
        float4 f0 = *(const float4*)(s);
        float4 f1 = *(const float4*)(s + 4);
        v[0] = (__bf16)f0.x; v[1] = (__bf16)f0.y; v[2] = (__bf16)f0.z; v[3] = (__bf16)f0.w;
        v[4] = (__bf16)f1.x; v[5] = (__bf16)f1.y; v[6] = (__bf16)f1.z; v[7] = (__bf16)f1.w;
        if (c7 == 0) bias_g[n] = bias[omap[n]];
    } else {
        #pragma unroll
        for (int e = 0; e < 8; ++e) v[e] = (__bf16)0.f;
        if (c7 == 0) bias_g[n] = 0.f;
    }
    *(bf16x8*)(wbf + (size_t)idx * 8) = v;
}

__global__ __launch_bounds__(256) void conv_x(
    const float* __restrict__ x, __bf16* __restrict__ xbf)
{
    int idx = blockIdx.x * 256 + threadIdx.x;   // B_*128 units
    int m   = idx >> 7;
    int c7  = idx & 127;
    int g = (m >> 1) & 3;
    int chunk = c7 >> 2, w = c7 & 3;
    const float* s = x + (size_t)m * H_ + chunk * 32 + ((w ^ g) << 3);
    float4 f0 = *(const float4*)(s);
    float4 f1 = *(const float4*)(s + 4);
    bf16x8 v;
    v[0] = (__bf16)f0.x; v[1] = (__bf16)f0.y; v[2] = (__bf16)f0.z; v[3] = (__bf16)f0.w;
    v[4] = (__bf16)f1.x; v[5] = (__bf16)f1.y; v[6] = (__bf16)f1.z; v[7] = (__bf16)f1.w;
    *(bf16x8*)(xbf + (size_t)idx * 8) = v;
}

// ---------------- GEMM: m97-style global_load_lds pipeline ------------------
template<bool FUSED>
__global__ __launch_bounds__(256) void gemm_kernel(
    const __bf16* __restrict__ xbf, const __bf16* __restrict__ wbf,
    const float* __restrict__ bias_g, const int* __restrict__ amask,
    float* __restrict__ out_scores, float* __restrict__ gen_masked,
    float* __restrict__ rowsum)
{
    __shared__ __bf16 As[2][BM * BKK];
    __shared__ __bf16 Bs[2][BN * BKK];

    // XCD swizzle: XCD r owns column tiles [49r,49r+49) x all 8 row-blocks
    const int id = (int)(blockIdx.x + (blockIdx.y << 3));   // gridDim.x == 8
    const int g  = id >> 3;
    const int by = (id & 7) * 49 + (g >> 3);                // 0..391
    if (by >= 391) return;
    const int bx = g & 7;
    const int m0 = bx * BM;
    const int n0 = by * BN;

    const int t    = threadIdx.x;
    const int wv   = t >> 6;
    const int lane = t & 63;
    const int quad = lane >> 4;
    const int lr   = lane & 15;
    const int wm   = (wv >> 1) * 64;
    const int wn   = (wv & 1) * 64;

    // per-lane global source (linear: data is pre-swizzled in global)
    const __bf16* gA = xbf + (size_t)(m0 + wv * 16 + (lane >> 2)) * H_ + ((lane & 3) << 3);
    const __bf16* gB = wbf + (size_t)(n0 + wv * 16 + (lane >> 2)) * H_ + ((lane & 3) << 3);

    auto stage = [&](int buf, int k) {
        __bf16* a = &As[0][0] + buf * (BM * BKK) + (wv * 16) * BKK;
        __bf16* b = &Bs[0][0] + buf * (BN * BKK) + (wv * 16) * BKK;
        ldsload16(gA + k,            a);
        ldsload16(gA + 64 * H_ + k,  a + 64 * BKK);
        ldsload16(gB + k,            b);
        ldsload16(gB + 64 * H_ + k,  b + 64 * BKK);
    };

    f32x4 acc[4][4];
    #pragma unroll
    for (int i = 0; i < 4; ++i)
        #pragma unroll
        for (int j = 0; j < 4; ++j)
            acc[i][j] = (f32x4){0.f, 0.f, 0.f, 0.f};

    auto compute = [&](int buf) {
        const __bf16* a  = &As[0][0] + buf * (BM * BKK);
        const __bf16* bp = &Bs[0][0] + buf * (BN * BKK);
        bf16x8 af[4], bfr[4];
        #pragma unroll
        for (int i = 0; i < 4; ++i) {
            int Ra = wm + i * 16 + lr;
            int Rb = wn + i * 16 + lr;
            af[i]  = *(const bf16x8*)(a  + Ra * BKK + ((quad ^ ((Ra >> 1) & 3)) << 3));
            bfr[i] = *(const bf16x8*)(bp + Rb * BKK + ((quad ^ ((Rb >> 1) & 3)) << 3));
        }
        #pragma unroll
        for (int mi = 0; mi < 4; ++mi)
            #pragma unroll
            for (int ni = 0; ni < 4; ++ni)
                acc[mi][ni] = __builtin_amdgcn_mfma_f32_16x16x32_bf16(bfr[ni], af[mi], acc[mi][ni], 0, 0, 0);
    };

    stage(0, 0);
    __syncthreads();
    for (int ts = 0; ts < NSTEP; ++ts) {
        int cur = ts & 1;
        if (ts + 1 < NSTEP) stage(cur ^ 1, (ts + 1) * BKK);
        compute(cur);
        __syncthreads();
    }

    // epilogue: lane owns 4 consecutive n at fixed m=lr (operand-swapped layout)
    #pragma unroll
    for (int mi = 0; mi < 4; ++mi) {
        const int m = m0 + wm + mi * 16 + lr;
        float psum = 0.0f;
        #pragma unroll
        for (int ni = 0; ni < 4; ++ni) {
            const int n = n0 + wn + ni * 16 + (quad << 2);
            if (n < VOUT) {
                const size_t off = (size_t)m * VOUT + n;
                const float4 bb = *(const float4*)(bias_g + n);
                float4 v;
                v.x = acc[mi][ni][0] + bb.x;
                v.y = acc[mi][ni][1] + bb.y;
                v.z = acc[mi][ni][2] + bb.z;
                v.w = acc[mi][ni][3] + bb.w;
                *(float4*)(out_scores + off) = v;
                if (FUSED) {
                    const int4 am = *(const int4*)(amask + off);
                    float4 gm;
                    gm.x = v.x - 1000000.0f * (float)am.x;
                    gm.y = v.y - 1000000.0f * (float)am.y;
                    gm.z = v.z - 1000000.0f * (float)am.z;
                    gm.w = v.w - 1000000.0f * (float)am.w;
                    *(float4*)(gen_masked + off) = gm;
                }
                psum += __expf(v.x) + __expf(v.y) + __expf(v.z) + __expf(v.w);
            }
        }
        psum += __shfl_xor(psum, 16, 64);
        psum += __shfl_xor(psum, 32, 64);
        if (quad == 0) atomicAdd(rowsum + m, psum);
    }
}

// ---------------- gen_masked = scores - 1e6*amask (fallback path) -----------
__global__ __launch_bounds__(256) void mask_kernel(
    const float* __restrict__ scores, const int* __restrict__ amask,
    float* __restrict__ gen)
{
    size_t i = (size_t)blockIdx.x * 256 + threadIdx.x;   // B_*VOUT/4 threads
    const float4 s = ((const float4*)scores)[i];
    const int4  a = ((const int4*)amask)[i];
    float4 gm;
    gm.x = s.x - 1000000.0f * (float)a.x;
    gm.y = s.y - 1000000.0f * (float)a.y;
    gm.z = s.z - 1000000.0f * (float)a.z;
    gm.w = s.w - 1000000.0f * (float)a.w;
    ((float4*)gen)[i] = gm;
}

// ---------------- ptr scatter-add + telescoping rowsum correction -----------
__global__ void ptr_scatter_kernel(const float* __restrict__ attn,
                                   const int* __restrict__ ctx,
                                   const int* __restrict__ i2a,
                                   const int* __restrict__ src_inp,
                                   float* __restrict__ out_scores,
                                   float* __restrict__ rowsum)
{
    int idx = blockIdx.x * blockDim.x + threadIdx.x;   // B*SRC threads
    int i = idx >> 8;
    int v = ctx[idx];
    int o = i2a[v];
    if (src_inp[o] == v) {
        float a   = attn[idx];
        float old = atomicAdd(out_scores + (size_t)i * VOUT + o, a);
        atomicAdd(rowsum + i, __expf(old + a) - __expf(old));
    }
}

// ---------------- single-pass normalize: p = exp(v) / rowsum ----------------
__global__ __launch_bounds__(256) void norm_kernel(float* __restrict__ probs,
                                                   const float* __restrict__ rowsum)
{
    const int row = blockIdx.x;
    const float inv = 1.0f / rowsum[row];
    float4* p4 = (float4*)(probs + (size_t)row * VOUT);
    const int base = blockIdx.y * 3125;                 // 4 segs * 3125 * 4 = 50000
    for (int i = base + threadIdx.x; i < base + 3125; i += 256) {
        float4 v = p4[i];
        v.x = __expf(v.x) * inv;
        v.y = __expf(v.y) * inv;
        v.z = __expf(v.z) * inv;
        v.w = __expf(v.w) * inv;
        p4[i] = v;
    }
}

// ---------------- launch ----------------------------------------------------
extern "C" void kernel_launch(void* const* d_in, const int* in_sizes, int n_in,
                              void* d_out, int out_size, void* d_ws, size_t ws_size,
                              hipStream_t stream)
{
    const float* x     = (const float*)d_in[0];
    const float* W     = (const float*)d_in[1];
    const float* b     = (const float*)d_in[2];
    const float* attn  = (const float*)d_in[3];
    const int*   ctx   = (const int*)d_in[4];
    const int*   i2a   = (const int*)d_in[5];
    const int*   omap  = (const int*)d_in[6];
    const int*   amask = (const int*)d_in[7];

    float* out_probs  = (float*)d_out;                       // B*VOUT
    float* gen_masked = out_probs + (size_t)B_ * VOUT;       // B*VOUT

    int*   src_inp = (int*)d_ws;                             // VOUT ints
    float* rowsum  = (float*)(src_inp + VOUT);               // B floats

    // scratch: W_bf (NPAD x H bf16) + x_bf (B x H bf16) + bias_g (NPAD f32)
    const size_t scratch_bytes = (size_t)NPAD * H_ * 2 + (size_t)B_ * H_ * 2 + (size_t)NPAD * 4;
    const size_t ws_need = (size_t)VOUT * 4 + (size_t)B_ * 4 + scratch_bytes;
    const bool ws_big = ws_size >= ws_need + 1024;
    // fallback: scratch lives in the gen_masked output region (dead until mask pass)
    char* scratch = ws_big ? (char*)(rowsum + B_) : (char*)gen_masked;
    __bf16* wbf    = (__bf16*)scratch;
    __bf16* xbf    = wbf + (size_t)NPAD * H_;
    float*  bias_g = (float*)(xbf + (size_t)B_ * H_);

    init_kernel<<<(VOUT + 255) / 256, 256, 0, stream>>>(src_inp, rowsum);
    scat_max_kernel<<<(VINP + 255) / 256, 256, 0, stream>>>(i2a, src_inp);
    conv_w<<<NPAD * 128 / 256, 256, 0, stream>>>(W, omap, b, wbf, bias_g);
    conv_x<<<B_ * 128 / 256, 256, 0, stream>>>(x, xbf);

    dim3 grid(B_ / BM, 392);                                 // 8*392 padded for swizzle
    if (ws_big) {
        gemm_kernel<true><<<grid, 256, 0, stream>>>(xbf, wbf, bias_g, amask,
                                                    out_probs, gen_masked, rowsum);
    } else {
        gemm_kernel<false><<<grid, 256, 0, stream>>>(xbf, wbf, bias_g, nullptr,
                                                     out_probs, nullptr, rowsum);
        mask_kernel<<<B_ * VOUT / 4 / 256, 256, 0, stream>>>(out_probs, amask, gen_masked);
    }

    ptr_scatter_kernel<<<(B_ * SRC_) / 256, 256, 0, stream>>>(attn, ctx, i2a, src_inp,
                                                              out_probs, rowsum);

    norm_kernel<<<dim3(B_, 4), 256, 0, stream>>>(out_probs, rowsum);
}